// Round 10
// baseline (77.611 us; speedup 1.0000x reference)
//
#include <hip/hip_runtime.h>

// NearestNeighbor b=8, d=256, n=m=4096.
// Round 10: counted-vmcnt phase pipeline (T3+T4+T5): ring-3 LDS half-buffers,
// vmcnt(8) steady-state (never 0 in loop), partC via LDS scratch (clean vmcnt).
// Frag-tiled fp8 panels, A-frags in registers. prep/finalize from r9 (verified).

typedef unsigned int uint;
typedef unsigned char uchar;
typedef int i32x4 __attribute__((ext_vector_type(4)));
typedef int i32x8 __attribute__((ext_vector_type(8)));
typedef float f32x4 __attribute__((ext_vector_type(4)));

constexpr int B_ = 8, D_ = 256, N_ = 4096;
constexpr int BMR = 128;                       // rows per block
constexpr int BNT = 128;                       // cols per tile iteration
constexpr int CSPLIT = 2;                      // column split
constexpr int MT_ITERS = (N_ / CSPLIT) / BNT;  // 16

// Unified frag-tiled panel layout (per batch, 1 MB):
// element (n,k): seg=n>>7, q=(n>>6)&1, r4=(n>>4)&3, i16=n&15;
//               ks=k>>7, g=(k>>5)&3, h=(k>>4)&1, kb=k&15
// off = seg*32768 + ks*16384 + ((q*4+r4)*2+h)*1024 + (g*16+i16)*16 + kb

// workspace layout (bytes)
constexpr size_t SZ_PANEL = (size_t)B_ * N_ * D_;        // 8.39 MB (fp8)
constexpr size_t OFF_AT = 0;
constexpr size_t OFF_BT = SZ_PANEL;
constexpr size_t OFF_PR = 2 * SZ_PANEL;                  // row partials: 4 slots
constexpr size_t SZ_PR  = (size_t)4 * B_ * N_ * 8;       // 1 MB
constexpr size_t OFF_PC = OFF_PR + SZ_PR;                // col partials: 64 slots

// f32 -> OCP e4m3fn (RNE, saturating).
__device__ __forceinline__ uchar f2e4m3(float f) {
  uint u = __float_as_uint(f);
  uint s = (u >> 24) & 0x80u;
  uint mag = u & 0x7FFFFFFFu;
  if (mag >= 0x43E00000u) return (uchar)(s | 0x7Eu);
  int e = (int)(mag >> 23) - 127;
  if (e >= -6) {
    uint m = (mag >> 20) & 7u;
    uint rem = mag & 0xFFFFFu;
    m += (rem > 0x80000u) || (rem == 0x80000u && (m & 1u));
    uint ef = (uint)(e + 7);
    if (m == 8u) { m = 0u; ef += 1u; }
    if (ef >= 16u) return (uchar)(s | 0x7Eu);
    return (uchar)(s | (ef << 3) | m);
  } else {
    int q = __float2int_rn(__uint_as_float(mag) * 512.0f);
    if (q >= 8) return (uchar)(s | 0x08u);
    return (uchar)(s | (uint)q);
  }
}

__device__ __forceinline__ void glds16(const void* g, void* l) {
  __builtin_amdgcn_global_load_lds(
      (const __attribute__((address_space(1))) void*)(uintptr_t)(g),
      (__attribute__((address_space(3))) void*)(uint32_t)(uintptr_t)(l),
      16, 0, 0);
}

__device__ __forceinline__ float packkey(float v, uint mask, uint tag) {
  return __uint_as_float((__float_as_uint(v) & mask) | tag);
}

__device__ __forceinline__ float med3f(float a, float b, float c) {
#if __has_builtin(__builtin_amdgcn_fmed3f)
  return __builtin_amdgcn_fmed3f(a, b, c);
#else
  return fmaxf(fminf(a, b), fminf(fmaxf(a, b), c));
#endif
}

__device__ __forceinline__ void top2p(float& s1, float& s2, float k0, float k1) {
  const float mid = med3f(s1, k0, k1);
  s1 = fmaxf(fmaxf(s1, k0), k1);
  s2 = fmaxf(s2, mid);
}

__device__ __forceinline__ void top2merge(float& s1, float& s2, float o1, float o2) {
  const float lo = fminf(s1, o1);
  s1 = fmaxf(s1, o1);
  s2 = fmaxf(lo, fmaxf(s2, o2));
}

#define CFENCE() asm volatile("" ::: "memory")
#define BARRIER() do { CFENCE(); __builtin_amdgcn_s_barrier(); CFENCE(); } while (0)

// ---- prep: [b][256][4096] f32 -> frag-tiled fp8 panel (verified r8/r9) ----
__global__ __launch_bounds__(256)
void prep_kernel(const float* __restrict__ in0, const float* __restrict__ in1,
                 uchar* __restrict__ At, uchar* __restrict__ Bt)
{
  __shared__ uchar tile[128][44];
  const int bz = blockIdx.z;
  const float* src = (bz < 8) ? in0 : in1;
  uchar* dst = (bz < 8) ? At : Bt;
  const int b = bz & 7;
  const int n0 = blockIdx.x * 128;
  const int k0b = blockIdx.y * 32;
  const int t = threadIdx.x;

  const int kq = t >> 5;
  const int n4 = (t & 31) * 4;
  const float* pin = src + ((size_t)b * D_ + k0b + kq * 4) * N_ + n0 + n4;
  float4 v[4];
  #pragma unroll
  for (int j = 0; j < 4; ++j) v[j] = *(const float4*)(pin + (size_t)j * N_);
  #pragma unroll
  for (int i = 0; i < 4; ++i) {
    uchar4 o = make_uchar4(f2e4m3(((const float*)&v[0])[i]),
                           f2e4m3(((const float*)&v[1])[i]),
                           f2e4m3(((const float*)&v[2])[i]),
                           f2e4m3(((const float*)&v[3])[i]));
    *(uchar4*)&tile[n4 + i][kq * 4] = o;
  }
  __syncthreads();

  const int nl = t & 127, h = t >> 7;
  const int kg = k0b + h * 16;
  const int ks = kg >> 7, g = (kg >> 5) & 3, hh = (kg >> 4) & 1;
  const int q = (nl >> 6) & 1, r4 = (nl >> 4) & 3, i16 = nl & 15;
  i32x4 val;
  #pragma unroll
  for (int j = 0; j < 4; ++j)
    val[j] = *(const int*)&tile[nl][h * 16 + j * 4];
  uchar* po = dst + (size_t)b * (N_ * D_) + (size_t)blockIdx.x * 32768 +
              ks * 16384 + ((q * 4 + r4) * 2 + hh) * 1024 + (g * 16 + i16) * 16;
  *(i32x4*)po = val;
}

// ---- fused GEMM (MX-fp8 K=128) + dual-direction top-2, counted-vmcnt pipeline ----
__global__ __launch_bounds__(256, 2)
void nn_pass(const uchar* __restrict__ A, const uchar* __restrict__ Bp,
             uint2* __restrict__ partR, uint2* __restrict__ partC)
{
  __shared__ uchar ring[3][16384];   // 48 KB: ring of K-half buffers
  __shared__ uint2 scrC[4096];       // 32 KB: col-partial scratch [mt][wm][wn][ni][l15]

  const int t = threadIdx.x;
  const int bid = blockIdx.x;
  const int b = bid & 7;                   // XCD-pinned batch
  const int rb = (bid >> 3) & 31;
  const int cs = bid >> 8;                 // 0..1
  const size_t bOff = (size_t)b * (N_ * D_);
  const int r0 = rb * BMR;

  const int l = t & 63, wid = t >> 6, wm = wid >> 1, wn = wid & 1;
  const int l15 = l & 15, g = l >> 4;
  const int lds0 = t * 16;

  const uchar* Aseg = A + bOff + (size_t)rb * 32768;
  const uchar* Bb = Bp + bOff + (size_t)cs * 524288;   // cs half: 16 tiles x 32KB

  // ---- A-frags from global (coalesced, L2-hot) ----
  i32x8 af[2][4];
  #pragma unroll
  for (int ks = 0; ks < 2; ++ks)
    #pragma unroll
    for (int mi = 0; mi < 4; ++mi) {
      const uchar* p = Aseg + ks * 16384 + ((wm * 4 + mi) * 2) * 1024 + l * 16;
      const i32x4 lo = *(const i32x4*)p;
      const i32x4 hi = *(const i32x4*)(p + 1024);
      af[ks][mi] = __builtin_shufflevector(lo, hi, 0, 1, 2, 3, 4, 5, 6, 7);
    }

  // stage a K-half (tile, ksl) into ring[slot]
  auto STAGE = [&](int tile, int ksl, int slot) {
    const uchar* src = Bb + (size_t)tile * 32768 + (size_t)ksl * 16384;
    char* dst = (char*)ring[slot];
    #pragma unroll
    for (int i = 0; i < 4; ++i)
      glds16(src + i * 4096 + lds0, dst + i * 4096 + lds0);
  };

  // 16 MFMAs of one K-half from ring[slot] with A-frags afk
  auto COMPUTE = [&](int slot, const i32x8 (&afk)[4], f32x4 (&acc)[4][4]) {
    const char* cB = (const char*)ring[slot] + l * 16;
    #pragma unroll
    for (int ni = 0; ni < 4; ++ni) {
      const int imm = ((wn * 4 + ni) * 2) * 1024;
      const i32x4 lo = *(const i32x4*)(cB + imm);
      const i32x4 hi = *(const i32x4*)(cB + imm + 1024);
      const i32x8 bf = __builtin_shufflevector(lo, hi, 0, 1, 2, 3, 4, 5, 6, 7);
      __builtin_amdgcn_s_setprio(1);
      #pragma unroll
      for (int mi = 0; mi < 4; ++mi)
        acc[mi][ni] = __builtin_amdgcn_mfma_scale_f32_16x16x128_f8f6f4(
            afk[mi], bf, acc[mi][ni], 0, 0, 0, 127, 0, 127);
      __builtin_amdgcn_s_setprio(0);
    }
  };

  const float NEG = __uint_as_float(0xFF800000u);  // -inf
  float rs1[4][4], rs2[4][4];
  #pragma unroll
  for (int mi = 0; mi < 4; ++mi)
    #pragma unroll
    for (int rg = 0; rg < 4; ++rg) { rs1[mi][rg] = NEG; rs2[mi][rg] = NEG; }

  // fold one tile's acc into rs (row dir) and scrC (col dir)
  auto FOLD = [&](int mt, f32x4 (&acc)[4][4]) {
    const int colb = mt * BNT + wn * 64;
    const uint tg0 = (uint)(2047 - (colb + l15));
    #pragma unroll
    for (int mi = 0; mi < 4; ++mi)
      #pragma unroll
      for (int rg = 0; rg < 4; ++rg) {
        const float k0 = packkey(acc[mi][0][rg], 0xFFFFF800u, tg0);
        const float k1 = packkey(acc[mi][1][rg], 0xFFFFF800u, tg0 - 16);
        const float k2 = packkey(acc[mi][2][rg], 0xFFFFF800u, tg0 - 32);
        const float k3 = packkey(acc[mi][3][rg], 0xFFFFF800u, tg0 - 48);
        top2p(rs1[mi][rg], rs2[mi][rg], k0, k1);
        top2p(rs1[mi][rg], rs2[mi][rg], k2, k3);
      }
    const uint tgb = (uint)(63 - g * 4);
    #pragma unroll
    for (int ni = 0; ni < 4; ++ni) {
      float c1 = NEG, c2 = NEG;
      #pragma unroll
      for (int mi = 0; mi < 4; ++mi) {
        const float k0 = packkey(acc[mi][ni][0], 0xFFFFFFC0u, tgb - (uint)(mi * 16));
        const float k1 = packkey(acc[mi][ni][1], 0xFFFFFFC0u, tgb - (uint)(mi * 16 + 1));
        const float k2 = packkey(acc[mi][ni][2], 0xFFFFFFC0u, tgb - (uint)(mi * 16 + 2));
        const float k3 = packkey(acc[mi][ni][3], 0xFFFFFFC0u, tgb - (uint)(mi * 16 + 3));
        top2p(c1, c2, k0, k1);
        top2p(c1, c2, k2, k3);
      }
      #pragma unroll
      for (int off = 16; off <= 32; off <<= 1) {
        const float o1 = __shfl_xor(c1, off);
        const float o2 = __shfl_xor(c2, off);
        top2merge(c1, c2, o1, o2);
      }
      if (g == 0)
        scrC[(((mt * 2 + wm) * 2 + wn) * 4 + ni) * 16 + l15] =
            make_uint2(__float_as_uint(c1), __float_as_uint(c2));
    }
  };

  // ---- prologue: stages 0,1 staged; drain everything once ----
  STAGE(0, 0, 0);
  STAGE(0, 1, 1);
  asm volatile("s_waitcnt vmcnt(0)" ::: "memory");
  BARRIER();

  int rcur = 0;   // ring slot of stage s = 2*mt

  #pragma unroll 1
  for (int mt = 0; mt < MT_ITERS - 1; ++mt) {
    f32x4 acc[4][4];
    #pragma unroll
    for (int mi = 0; mi < 4; ++mi)
      #pragma unroll
      for (int ni = 0; ni < 4; ++ni) acc[mi][ni] = (f32x4){0.f, 0.f, 0.f, 0.f};

    int rn2 = rcur + 2; if (rn2 >= 3) rn2 -= 3;
    int rn1 = rcur + 1; if (rn1 >= 3) rn1 -= 3;

    // stage A (s=2mt): issue s+2 (tile mt+1, ks0); wait counted; compute ks0
    STAGE(mt + 1, 0, rn2);
    asm volatile("s_waitcnt vmcnt(8)" ::: "memory");
    BARRIER();
    COMPUTE(rcur, af[0], acc);
    BARRIER();

    // stage B (s=2mt+1): issue s+2 (tile mt+1, ks1) into rcur's slot; compute ks1
    STAGE(mt + 1, 1, rcur);
    asm volatile("s_waitcnt vmcnt(8)" ::: "memory");
    BARRIER();
    COMPUTE(rn1, af[1], acc);
    FOLD(mt, acc);
    BARRIER();

    rcur = rn2;
  }

  // ---- tail tile 15: no further staging; peel vmcnt 4 -> 0 ----
  {
    f32x4 acc[4][4];
    #pragma unroll
    for (int mi = 0; mi < 4; ++mi)
      #pragma unroll
      for (int ni = 0; ni < 4; ++ni) acc[mi][ni] = (f32x4){0.f, 0.f, 0.f, 0.f};
    int rn1 = rcur + 1; if (rn1 >= 3) rn1 -= 3;

    asm volatile("s_waitcnt vmcnt(4)" ::: "memory");
    BARRIER();
    COMPUTE(rcur, af[0], acc);
    BARRIER();

    asm volatile("s_waitcnt vmcnt(0)" ::: "memory");
    BARRIER();
    COMPUTE(rn1, af[1], acc);
    FOLD(MT_ITERS - 1, acc);
    BARRIER();
  }

  // ---- epilogue 1: dump scrC -> partC (coalesced, 128B/thread) ----
  {
    const int wmD = t >> 7;                 // 0..1
    const int cc = t & 127;                 // 16-col group: c = cc*16 + j
    const uint2* sp = &scrC[(size_t)(((cc >> 3) * 2 + wmD) * 2 + ((cc >> 2) & 1)) * 64 +
                            (cc & 3) * 16];
    uint2* gp = partC + ((size_t)(rb * 2 + wmD) * B_ + b) * N_ + cs * 2048 + cc * 16;
    #pragma unroll
    for (int j = 0; j < 16; ++j) gp[j] = sp[j];
  }

  // ---- epilogue 2: row merge across 16 column-lanes, write partR ----
  #pragma unroll
  for (int off = 1; off < 16; off <<= 1) {
    #pragma unroll
    for (int mi = 0; mi < 4; ++mi)
      #pragma unroll
      for (int rg = 0; rg < 4; ++rg) {
        const float o1 = __shfl_xor(rs1[mi][rg], off);
        const float o2 = __shfl_xor(rs2[mi][rg], off);
        top2merge(rs1[mi][rg], rs2[mi][rg], o1, o2);
      }
  }
  if (l15 == 0) {
    #pragma unroll
    for (int mi = 0; mi < 4; ++mi)
      #pragma unroll
      for (int rg = 0; rg < 4; ++rg)
        partR[((size_t)(cs * 2 + wn) * B_ + b) * N_ + r0 + wm * 64 + mi * 16 + g * 4 + rg] =
            make_uint2(__float_as_uint(rs1[mi][rg]), __float_as_uint(rs2[mi][rg]));
  }
}

// ---- fused: fold partials, ratio test, mutual check, output (verified r9) ----
__global__ __launch_bounds__(256)
void finalize_kernel(const uint2* __restrict__ pR, const uint2* __restrict__ pC,
                     float* __restrict__ out)
{
  const int i = blockIdx.x * 256 + threadIdx.x;
  if (i >= B_ * N_) return;
  const int b = i >> 12;
  const int n = i & (N_ - 1);
  const float NEG = __uint_as_float(0xFF800000u);

  float s1 = NEG, s2 = NEG; int bs = 0;
  #pragma unroll
  for (int sl = 0; sl < 4; ++sl) {
    const uint2 v = pR[(size_t)sl * B_ * N_ + i];
    const float o1 = __uint_as_float(v.x), o2 = __uint_as_float(v.y);
    bs = (o1 > s1) ? sl : bs;
    top2merge(s1, s2, o1, o2);
  }
  const uint k1 = __float_as_uint(s1);
  const int col = (bs >> 1) * 2048 + 2047 - (int)(k1 & 0x7FFu);
  const float v1 = __uint_as_float(k1 & 0xFFFFF800u);
  const float v2 = __uint_as_float(__float_as_uint(s2) & 0xFFFFF800u);
  const bool ok = (1.0f - v1) <= 0.64f * (1.0f - v2);   // Lowe 0.8^2

  out[B_ * N_ + i] = ok ? (v1 + 1.0f) * 0.5f : 0.0f;    // scores0 (no mutual mask)

  int res = -1;
  if (ok) {
    float c1 = NEG, c2 = NEG; int cbs = 0;
    const uint2* pcb = pC + (size_t)b * N_ + col;
    #pragma unroll 8
    for (int sl = 0; sl < 64; ++sl) {
      const uint2 v = pcb[(size_t)sl * B_ * N_];
      const float o1 = __uint_as_float(v.x), o2 = __uint_as_float(v.y);
      cbs = (o1 > c1) ? sl : cbs;
      top2merge(c1, c2, o1, o2);
    }
    const uint ck1 = __float_as_uint(c1);
    const int row = cbs * 64 + 63 - (int)(ck1 & 0x3Fu);
    const float cv1 = __uint_as_float(ck1 & 0xFFFFFFC0u);
    const float cv2 = __uint_as_float(__float_as_uint(c2) & 0xFFFFFFC0u);
    const bool cok = (1.0f - cv1) <= 0.64f * (1.0f - cv2);
    if (cok && row == n) res = col;
  }
  out[i] = (float)res;
}

extern "C" void kernel_launch(void* const* d_in, const int* in_sizes, int n_in,
                              void* d_out, int out_size, void* d_ws, size_t ws_size,
                              hipStream_t stream)
{
  const float* d0 = (const float*)d_in[0];
  const float* d1 = (const float*)d_in[1];
  float* out = (float*)d_out;

  uchar* At = (uchar*)((char*)d_ws + OFF_AT);
  uchar* Bt = (uchar*)((char*)d_ws + OFF_BT);
  uint2* PR = (uint2*)((char*)d_ws + OFF_PR);
  uint2* PC = (uint2*)((char*)d_ws + OFF_PC);

  prep_kernel<<<dim3(N_ / 128, D_ / 32, 16), 256, 0, stream>>>(d0, d1, At, Bt);
  nn_pass<<<dim3(B_ * (N_ / BMR) * CSPLIT), 256, 0, stream>>>(At, Bt, PR, PC);
  finalize_kernel<<<dim3(B_ * N_ / 256), 256, 0, stream>>>(PR, PC, out);
}